// Round 4
// baseline (96.317 us; speedup 1.0000x reference)
//
#include <hip/hip_runtime.h>
#include <math.h>

#define N 512
#define TILE 32
#define TPB 4  // tile-pairs per block (136 = 34 * 4)

struct F3 { float x, y, z; };

__device__ __forceinline__ F3 f3sub(F3 a, F3 b) { return {a.x - b.x, a.y - b.y, a.z - b.z}; }
__device__ __forceinline__ F3 f3cross(F3 a, F3 b) {
    return {a.y * b.z - a.z * b.y, a.z * b.x - a.x * b.z, a.x * b.y - a.y * b.x};
}
__device__ __forceinline__ float f3dot(F3 a, F3 b) { return a.x * b.x + a.y * b.y + a.z * b.z; }

__device__ __forceinline__ F3 ldp(const float4* __restrict__ xs4, int i) {
    float4 q = xs4[i];
    return {q.x, q.y, q.z};
}

// Abramowitz-Stegun 4.4.45: |err| <= 5e-5, branch-free.
// __builtin_amdgcn_sqrtf = raw v_sqrt_f32 (no IEEE fixup sequence).
__device__ __forceinline__ float fast_asinf(float x) {
    float ax = fabsf(x);
    float p = fmaf(ax, -0.0187293f, 0.0742610f);
    p = fmaf(ax, p, -0.2121144f);
    p = fmaf(ax, p, 1.5707288f);
    float r = 1.5707963267948966f - __builtin_amdgcn_sqrtf(1.0f - ax) * p;
    return copysignf(r, x);
}

__device__ __forceinline__ float wr_core(F3 p0, F3 p1, F3 p2, F3 p3) {
    // Normalization of displacements cancels in normalized crosses and in the sign term.
    F3 d0 = f3sub(p2, p0), d1 = f3sub(p3, p0), d2 = f3sub(p2, p1), d3 = f3sub(p3, p1);

    F3 c0 = f3cross(d0, d1);
    F3 c1 = f3cross(d1, d3);
    F3 c2 = f3cross(d3, d2);
    F3 c3 = f3cross(d2, d0);

    float r0 = rsqrtf(f3dot(c0, c0));
    float r1 = rsqrtf(f3dot(c1, c1));
    float r2 = rsqrtf(f3dot(c2, c2));
    float r3 = rsqrtf(f3dot(c3, c3));

    float t01 = fminf(1.f, fmaxf(-1.f, f3dot(c0, c1) * (r0 * r1)));
    float t12 = fminf(1.f, fmaxf(-1.f, f3dot(c1, c2) * (r1 * r2)));
    float t23 = fminf(1.f, fmaxf(-1.f, f3dot(c2, c3) * (r2 * r3)));
    float t30 = fminf(1.f, fmaxf(-1.f, f3dot(c3, c0) * (r3 * r0)));

    float omega = fast_asinf(t01) + fast_asinf(t12) + fast_asinf(t23) + fast_asinf(t30);

    F3 e = f3cross(f3sub(p3, p2), f3sub(p1, p0));
    float sv = f3dot(e, d0);
    float sgn = (sv > 0.f) ? 1.f : ((sv < 0.f) ? -1.f : 0.f);

    return omega * sgn * 0.15915494309189535f;  // 1/(2*pi)
}

// One block per (group of TPB tile-pairs, batch). x staged to LDS once per block.
// Each tile: compute 32x32, write it + transpose via LDS bounce, fully coalesced.
__global__ __launch_bounds__(256) void writhe_tile(const float* __restrict__ x,
                                                   float* __restrict__ out) {
    __shared__ __align__(16) float4 xs4[N];  // 16B stride -> ds_read_b128 point loads
    __shared__ float ts[TILE][TILE + 1];

    const int batch = blockIdx.y;

    // Coalesced float4 staging with stride-3 -> stride-4 repack (scalar LDS writes are cheap).
    {
        const float4* src = (const float4*)(x + (size_t)batch * (N * 3));
        float* xsf = (float*)xs4;
        for (int i = threadIdx.x; i < (N * 3) / 4; i += blockDim.x) {
            float4 g = src[i];
            const int base = 4 * i;
            float vv[4] = {g.x, g.y, g.z, g.w};
#pragma unroll
            for (int j = 0; j < 4; ++j) {
                const int e = base + j;
                xsf[(e / 3) * 4 + (e % 3)] = vv[j];
            }
        }
    }
    __syncthreads();

    const int c = threadIdx.x & 31;
    const int r0 = threadIdx.x >> 5;
    float* ob = out + (size_t)batch * (N * N);

    for (int t = 0; t < TPB; ++t) {
        // Map pair index -> (ti, tj), ti <= tj, among 16x16 tiles (136 pairs).
        int p = blockIdx.x * TPB + t;
        int ti = 0;
        while (p >= (N / TILE) - ti) { p -= (N / TILE) - ti; ++ti; }
        const int tj = ti + p;
        const bool diag = (ti == tj);
        const int gj = tj * TILE + c;

        if (!diag) {
            // Off-diag: gj > gi always, so the b-segment (gj-1, gj) is constant per thread.
            const F3 p2 = ldp(xs4, gj - 1);
            const F3 p3 = ldp(xs4, gj);
#pragma unroll
            for (int k = 0; k < 4; ++k) {
                const int r = r0 + 8 * k;
                const int gi = ti * TILE + r;
                float v = 0.f;
                if (gi == 0) {
                    // lo==0 rule: segment (0, gj), valid for 2 <= gj <= 510.
                    if (gj <= 510) {
                        v = wr_core(ldp(xs4, 0), ldp(xs4, 1), ldp(xs4, gj), ldp(xs4, gj + 1));
                    }
                } else if (gj >= gi + 2) {
                    v = wr_core(ldp(xs4, gi - 1), ldp(xs4, gi), p2, p3);
                }
                ob[(size_t)gi * N + gj] = v;
                ts[r][c] = v;
            }
            __syncthreads();
#pragma unroll
            for (int k = 0; k < 4; ++k) {
                const int r = r0 + 8 * k;
                ob[(size_t)(tj * TILE + r) * N + (ti * TILE + c)] = ts[c][r];
            }
            __syncthreads();  // ts reused by next tile iteration
        } else {
            // Diagonal tile: generic per-element path (writes both triangles directly).
#pragma unroll
            for (int k = 0; k < 4; ++k) {
                const int r = r0 + 8 * k;
                const int gi = ti * TILE + r;
                const int lo = min(gi, gj), hi = max(gi, gj);
                bool valid;
                int a, b;
                if (lo == 0) { valid = (hi >= 2) && (hi <= 510); a = 0; b = hi; }
                else         { valid = (hi >= lo + 2);           a = lo - 1; b = hi - 1; }
                float v = 0.f;
                if (valid) v = wr_core(ldp(xs4, a), ldp(xs4, a + 1), ldp(xs4, b), ldp(xs4, b + 1));
                ob[(size_t)gi * N + gj] = v;
            }
        }
    }
}

extern "C" void kernel_launch(void* const* d_in, const int* in_sizes, int n_in,
                              void* d_out, int out_size, void* d_ws, size_t ws_size,
                              hipStream_t stream) {
    const float* x = (const float*)d_in[0];
    float* out = (float*)d_out;
    const int B = in_sizes[0] / (N * 3);

    const int ntiles = N / TILE;                    // 16
    const int npairs = ntiles * (ntiles + 1) / 2;   // 136
    const int ngroups = (npairs + TPB - 1) / TPB;   // 34

    dim3 block(256);
    dim3 grid(ngroups, B);
    writhe_tile<<<grid, block, 0, stream>>>(x, out);
}

// Round 5
// 82.129 us; speedup vs baseline: 1.1728x; 1.1728x over previous
//
#include <hip/hip_runtime.h>
#include <math.h>

#define N 512
#define TILE 32
#define INV2PI 0.15915494309189535f

// ---- packed (2-element-per-lane) float2 helpers: lowered to v_pk_*_f32 ----
__device__ __forceinline__ float2 pset(float a, float b) { return make_float2(a, b); }
__device__ __forceinline__ float2 psplat(float a) { return make_float2(a, a); }
__device__ __forceinline__ float2 p_sub(float2 a, float2 b) { return make_float2(a.x - b.x, a.y - b.y); }
__device__ __forceinline__ float2 p_mul(float2 a, float2 b) { return make_float2(a.x * b.x, a.y * b.y); }
__device__ __forceinline__ float2 p_fma(float2 a, float2 b, float2 c) {
    return make_float2(fmaf(a.x, b.x, c.x), fmaf(a.y, b.y, c.y));
}
// a*b - c*d  (fused)
__device__ __forceinline__ float2 p_fmsub(float2 a, float2 b, float2 c, float2 d) {
    return make_float2(fmaf(a.x, b.x, -(c.x * d.x)), fmaf(a.y, b.y, -(c.y * d.y)));
}
__device__ __forceinline__ float2 p_clamp1(float2 a) {
    return make_float2(fminf(1.f, fmaxf(-1.f, a.x)), fminf(1.f, fmaxf(-1.f, a.y)));
}
__device__ __forceinline__ float2 p_rsq(float2 a) {
    return make_float2(__builtin_amdgcn_rsqf(a.x), __builtin_amdgcn_rsqf(a.y));
}

struct F3P { float2 x, y, z; };

__device__ __forceinline__ F3P pp_sub(F3P a, F3P b) {
    return {p_sub(a.x, b.x), p_sub(a.y, b.y), p_sub(a.z, b.z)};
}
__device__ __forceinline__ F3P pp_cross(F3P a, F3P b) {
    F3P c;
    c.x = p_fmsub(a.y, b.z, a.z, b.y);
    c.y = p_fmsub(a.z, b.x, a.x, b.z);
    c.z = p_fmsub(a.x, b.y, a.y, b.x);
    return c;
}
__device__ __forceinline__ float2 pp_dot(F3P a, F3P b) {
    return p_fma(a.x, b.x, p_fma(a.y, b.y, p_mul(a.z, b.z)));
}

// Abramowitz-Stegun 4.4.45, |err| <= 5e-5; polynomial packed, sqrt per half.
__device__ __forceinline__ float2 p_asin(float2 v) {
    float2 ax = make_float2(fabsf(v.x), fabsf(v.y));
    float2 p = p_fma(ax, psplat(-0.0187293f), psplat(0.0742610f));
    p = p_fma(ax, p, psplat(-0.2121144f));
    p = p_fma(ax, p, psplat(1.5707288f));
    float2 s = make_float2(__builtin_amdgcn_sqrtf(1.0f - ax.x), __builtin_amdgcn_sqrtf(1.0f - ax.y));
    float2 r = make_float2(1.5707963267948966f - s.x * p.x, 1.5707963267948966f - s.y * p.y);
    return make_float2(copysignf(r.x, v.x), copysignf(r.y, v.y));
}

// Two independent writhe evaluations, one in each float2 half.
__device__ __forceinline__ float2 wr_core2(F3P p0, F3P p1, F3P p2, F3P p3) {
    // Displacement normalization cancels in normalized crosses and in the sign term.
    F3P d0 = pp_sub(p2, p0), d1 = pp_sub(p3, p0), d2 = pp_sub(p2, p1), d3 = pp_sub(p3, p1);

    F3P c0 = pp_cross(d0, d1);
    F3P c1 = pp_cross(d1, d3);
    F3P c2 = pp_cross(d3, d2);
    F3P c3 = pp_cross(d2, d0);

    float2 r0 = p_rsq(pp_dot(c0, c0));
    float2 r1 = p_rsq(pp_dot(c1, c1));
    float2 r2 = p_rsq(pp_dot(c2, c2));
    float2 r3 = p_rsq(pp_dot(c3, c3));

    float2 t01 = p_clamp1(p_mul(pp_dot(c0, c1), p_mul(r0, r1)));
    float2 t12 = p_clamp1(p_mul(pp_dot(c1, c2), p_mul(r1, r2)));
    float2 t23 = p_clamp1(p_mul(pp_dot(c2, c3), p_mul(r2, r3)));
    float2 t30 = p_clamp1(p_mul(pp_dot(c3, c0), p_mul(r3, r0)));

    float2 a01 = p_asin(t01), a12 = p_asin(t12), a23 = p_asin(t23), a30 = p_asin(t30);
    float2 omega = make_float2(a01.x + a12.x + a23.x + a30.x, a01.y + a12.y + a23.y + a30.y);

    F3P e = pp_cross(pp_sub(p3, p2), pp_sub(p1, p0));
    float2 sv = pp_dot(e, d0);
    float sgx = (sv.x > 0.f) ? 1.f : ((sv.x < 0.f) ? -1.f : 0.f);
    float sgy = (sv.y > 0.f) ? 1.f : ((sv.y < 0.f) ? -1.f : 0.f);

    return make_float2(omega.x * sgx * INV2PI, omega.y * sgy * INV2PI);
}

__device__ __forceinline__ F3P pack_pt(const float4* __restrict__ xs4, int i0, int i1) {
    float4 a = xs4[i0];
    float4 b = xs4[i1];
    F3P r;
    r.x = pset(a.x, b.x);
    r.y = pset(a.y, b.y);
    r.z = pset(a.z, b.z);
    return r;
}

// Per-element index rule (resolves the reference's two sequential overlapping scatters):
// out(lo,hi): lo>=1 & hi>=lo+2 -> segment (lo-1, hi-1); lo==0 & 2<=hi<=510 -> segment (0, hi).
__device__ __forceinline__ void elem_idx(int gi, int gj, int& a, int& b, bool& valid) {
    const int lo = min(gi, gj), hi = max(gi, gj);
    if (lo == 0) { valid = (hi >= 2) && (hi <= 510); a = 0; b = min(hi, 510); }
    else         { valid = (hi >= lo + 2);           a = lo - 1; b = hi - 1; }
}

// One block per (upper-triangle tile pair, batch). Each lane computes TWO output
// elements (rows r and r+16, same column) packed into float2 halves -> v_pk_*_f32.
__global__ __launch_bounds__(256) void writhe_tile(const float* __restrict__ x,
                                                   float* __restrict__ out) {
    __shared__ __align__(16) float4 xs4[N];
    __shared__ float ts[TILE][TILE + 1];

    const int batch = blockIdx.y;

    // Coalesced float4 global read, stride-3 -> stride-4 repack into LDS.
    {
        const float4* src = (const float4*)(x + (size_t)batch * (N * 3));
        float* xsf = (float*)xs4;
        for (int i = threadIdx.x; i < (N * 3) / 4; i += blockDim.x) {
            float4 g = src[i];
            const int base = 4 * i;
            float vv[4] = {g.x, g.y, g.z, g.w};
#pragma unroll
            for (int j = 0; j < 4; ++j) {
                const int e = base + j;
                xsf[(e / 3) * 4 + (e % 3)] = vv[j];
            }
        }
    }

    // blockIdx.x -> (ti, tj), ti <= tj, among 16x16 tiles (136 pairs).
    int p = blockIdx.x;
    int ti = 0;
    while (p >= (N / TILE) - ti) { p -= (N / TILE) - ti; ++ti; }
    const int tj = ti + p;
    const bool diag = (ti == tj);

    __syncthreads();

    const int c = threadIdx.x & 31;
    const int r0 = threadIdx.x >> 5;
    const int gj = tj * TILE + c;
    float* ob = out + (size_t)batch * (N * N);

#pragma unroll
    for (int k = 0; k < 2; ++k) {
        const int rA = r0 + 8 * k;        // half .x row
        const int rB = rA + 16;           // half .y row
        const int giA = ti * TILE + rA;
        const int giB = ti * TILE + rB;

        int aA, bA, aB, bB;
        bool vA, vB;
        elem_idx(giA, gj, aA, bA, vA);
        elem_idx(giB, gj, aB, bB, vB);

        F3P P0 = pack_pt(xs4, aA, aB);
        F3P P1 = pack_pt(xs4, aA + 1, aB + 1);
        F3P P2 = pack_pt(xs4, bA, bB);
        F3P P3 = pack_pt(xs4, bA + 1, bB + 1);

        float2 wr = wr_core2(P0, P1, P2, P3);
        const float vxA = vA ? wr.x : 0.f;
        const float vxB = vB ? wr.y : 0.f;

        ob[(size_t)giA * N + gj] = vxA;
        ob[(size_t)giB * N + gj] = vxB;
        if (!diag) {
            ts[rA][c] = vxA;
            ts[rB][c] = vxB;
        }
    }

    if (!diag) {
        __syncthreads();
#pragma unroll
        for (int k = 0; k < 4; ++k) {
            const int r = r0 + 8 * k;
            ob[(size_t)(tj * TILE + r) * N + (ti * TILE + c)] = ts[c][r];
        }
    }
}

extern "C" void kernel_launch(void* const* d_in, const int* in_sizes, int n_in,
                              void* d_out, int out_size, void* d_ws, size_t ws_size,
                              hipStream_t stream) {
    const float* x = (const float*)d_in[0];
    float* out = (float*)d_out;
    const int B = in_sizes[0] / (N * 3);

    const int ntiles = N / TILE;                   // 16
    const int npairs = ntiles * (ntiles + 1) / 2;  // 136

    dim3 block(256);
    dim3 grid(npairs, B);
    writhe_tile<<<grid, block, 0, stream>>>(x, out);
}